// Round 9
// baseline (2580.595 us; speedup 1.0000x reference)
//
#include <hip/hip_runtime.h>

#define N_INPUT 256
#define HS 32
#define SB 256   // scan block threads
#define SE 1024  // elems per scan block

typedef __attribute__((ext_vector_type(8))) short bf16x8;
typedef __attribute__((ext_vector_type(4))) float f32x4;
typedef __attribute__((ext_vector_type(4))) unsigned short u16x4;

// fp32 -> bf16 bits, round-to-nearest-even
__device__ __forceinline__ unsigned short f2bf(float f) {
    unsigned u = __float_as_uint(f);
    unsigned r = u + 0x7FFFu + ((u >> 16) & 1u);
    return (unsigned short)(r >> 16);
}
__device__ __forceinline__ float bf2f(unsigned short u) {
    return __uint_as_float((unsigned)u << 16);
}

// ---------------- CSR build ----------------
// R8 scatter postmortem: WRITE 72.5 MB for 6.4 MB of payload -- each XCD
// streamed the whole 12.8 MB edge list through its 4 MB L2, evicting dirty
// sorted_dst lines before they filled. Fix: bin first (sequential writes,
// no amplification possible), then scatter with a 1.6 MB L2-resident
// working set per XCD. deg histogram folded into the bin pass (XCD-local).

__global__ void init_kernel(int* __restrict__ deg, int* __restrict__ gcount, int N) {
    int i = blockIdx.x * blockDim.x + threadIdx.x;
    int stride = gridDim.x * blockDim.x;
    for (int j = i; j < N; j += stride) deg[j] = 0;
    if (i < 8) gcount[i] = 0;
}

// group g = blockIdx&7 (XCD round-robin) strides the edge list; in-range
// edges appended to bin[g] via wave-aggregated atomic (one atomicAdd/wave,
// coalesced sequential burst writes). Pack: (src-nlo)<<17 | dst
// (N/8=12500<2^14, dst<2^17). Also counts deg (XCD-local lines).
__global__ __launch_bounds__(256) void bin_kernel(
        const int* __restrict__ src, const int* __restrict__ dst,
        int* __restrict__ deg, unsigned* __restrict__ bins,
        int* __restrict__ gcount, int E, int N, int cap) {
    int g = blockIdx.x & 7;
    int nlo = (int)(((long long)N * g) >> 3);
    int nhi = (int)(((long long)N * (g + 1)) >> 3);
    unsigned* mybin = bins + (size_t)g * cap;
    int lane = threadIdx.x & 63;
    int stride = (gridDim.x >> 3) * blockDim.x;
    for (int e = (blockIdx.x >> 3) * blockDim.x + threadIdx.x; e < E; e += stride) {
        int s = src[e];
        int d = dst[e];
        bool inr = (s >= nlo) && (s < nhi);
        unsigned long long mask = __ballot(inr);
        if (inr) {
            int prefix = __popcll(mask & ((1ull << lane) - 1ull));
            int leader = __ffsll((unsigned long long)mask) - 1;
            int pos = 0;
            if (lane == leader) pos = atomicAdd(gcount + g, __popcll(mask));
            pos = __shfl(pos, leader, 64);
            mybin[pos + prefix] = ((unsigned)(s - nlo) << 17) | (unsigned)d;
            atomicAdd(deg + s, 1);
        }
    }
}

// 3-kernel device-wide exclusive scan (R6; R5's single-block scan was 231 us).
__global__ __launch_bounds__(SB) void block_reduce_kernel(
        const int* __restrict__ deg, int* __restrict__ bsum, int N) {
    __shared__ int s[SB];
    int blk = blockIdx.x, t = threadIdx.x;
    int base = blk * SE;
    int sum = 0;
#pragma unroll
    for (int i = 0; i < SE / SB; ++i) {
        int idx = base + i * SB + t;  // coalesced
        if (idx < N) sum += deg[idx];
    }
    s[t] = sum;
    __syncthreads();
    for (int off = SB / 2; off > 0; off >>= 1) {
        if (t < off) s[t] += s[t + off];
        __syncthreads();
    }
    if (t == 0) bsum[blk] = s[0];
}

__global__ __launch_bounds__(SB) void scan_sums_kernel(
        const int* __restrict__ bsum, int* __restrict__ boff, int nblocks,
        int* __restrict__ rowstart, int N, int E) {
    __shared__ int s[SB];
    int t = threadIdx.x;
    int v = (t < nblocks) ? bsum[t] : 0;
    s[t] = v;
    __syncthreads();
    for (int off = 1; off < SB; off <<= 1) {
        int u = (t >= off) ? s[t - off] : 0;
        __syncthreads();
        s[t] += u;
        __syncthreads();
    }
    if (t < nblocks) boff[t] = s[t] - v;  // exclusive block offset
    if (t == 0) rowstart[N] = E;
}

__global__ __launch_bounds__(SB) void emit_kernel(
        const int* __restrict__ deg, const int* __restrict__ boff,
        int* __restrict__ rowstart, int* __restrict__ cursor, int N) {
    __shared__ int s[SB];
    int blk = blockIdx.x, t = threadIdx.x;
    int base = blk * SE + t * 4;
    int4 d = make_int4(0, 0, 0, 0);
    if (base + 3 < N) {
        d = *(const int4*)(deg + base);
    } else {
        if (base + 0 < N) d.x = deg[base + 0];
        if (base + 1 < N) d.y = deg[base + 1];
        if (base + 2 < N) d.z = deg[base + 2];
    }
    int tsum = d.x + d.y + d.z + d.w;
    s[t] = tsum;
    __syncthreads();
    for (int off = 1; off < SB; off <<= 1) {
        int u = (t >= off) ? s[t - off] : 0;
        __syncthreads();
        s[t] += u;
        __syncthreads();
    }
    int pre = boff[blk] + s[t] - tsum;  // exclusive prefix of this thread's 1st elem
    int4 r;
    r.x = pre;
    r.y = r.x + d.x;
    r.z = r.y + d.y;
    r.w = r.z + d.z;
    if (base + 3 < N) {
        *(int4*)(rowstart + base) = r;
        *(int4*)(cursor + base) = r;
    } else {
        if (base + 0 < N) { rowstart[base + 0] = r.x; cursor[base + 0] = r.x; }
        if (base + 1 < N) { rowstart[base + 1] = r.y; cursor[base + 1] = r.y; }
        if (base + 2 < N) { rowstart[base + 2] = r.z; cursor[base + 2] = r.z; }
    }
}

// group g scatters only its own bin: reads 800KB sequential, writes its
// 800KB sorted_dst region, cursor atomics XCD-local -- everything L2-resident.
__global__ __launch_bounds__(256) void scatter2_kernel(
        const unsigned* __restrict__ bins, const int* __restrict__ gcount,
        int* __restrict__ cursor, int* __restrict__ sorted_dst, int cap, int N) {
    int g = blockIdx.x & 7;
    int nlo = (int)(((long long)N * g) >> 3);
    const unsigned* mybin = bins + (size_t)g * cap;
    int cnt = gcount[g];
    int stride = (gridDim.x >> 3) * blockDim.x;
    for (int i = (blockIdx.x >> 3) * blockDim.x + threadIdx.x; i < cnt; i += stride) {
        unsigned p = mybin[i];
        int s = nlo + (int)(p >> 17);
        int d = (int)(p & 0x1FFFFu);
        int pos = atomicAdd(cursor + s, 1);
        sorted_dst[pos] = d;
    }
}

// ---------------- Fused Q/K/V projection (MFMA, unchanged from R8) ----------------
__global__ __launch_bounds__(256) void qkv_mfma_kernel(
        const float* __restrict__ X, const float* __restrict__ Wq,
        const float* __restrict__ Wk, const float* __restrict__ Wv,
        float* __restrict__ Q, unsigned short* __restrict__ Kb,
        unsigned short* __restrict__ Vb, int N) {
    __shared__ unsigned short sB[6 * 8 * 64 * 8];  // 48 KB, frag-ordered bf16 W

    int tid = threadIdx.x;
    for (int i = 0; i < 12; ++i) {
        int c = tid + i * 256;
        int s = c >> 9;
        int t = (c >> 6) & 7;
        int L = c & 63;
        const float* wm = (s < 2) ? Wq : (s < 4) ? Wk : Wv;
        const float* wsrc = wm + (size_t)(t * 32 + (L >> 4) * 8) * HS + (s & 1) * 16 + (L & 15);
        unsigned e0 = f2bf(wsrc[0 * HS]) | ((unsigned)f2bf(wsrc[1 * HS]) << 16);
        unsigned e1 = f2bf(wsrc[2 * HS]) | ((unsigned)f2bf(wsrc[3 * HS]) << 16);
        unsigned e2 = f2bf(wsrc[4 * HS]) | ((unsigned)f2bf(wsrc[5 * HS]) << 16);
        unsigned e3 = f2bf(wsrc[6 * HS]) | ((unsigned)f2bf(wsrc[7 * HS]) << 16);
        ((uint4*)sB)[c] = make_uint4(e0, e1, e2, e3);
    }
    __syncthreads();

    int wave = tid >> 6;
    int L = tid & 63;
    int quad = L >> 4;
    int lane16 = L & 15;
    int mt = blockIdx.x * 4 + wave;
    if (mt * 16 >= N) return;  // no barriers past this point

    const float* xrow = X + (size_t)(mt * 16 + lane16) * N_INPUT + quad * 8;
    bf16x8 afrag[8];
#pragma unroll
    for (int t = 0; t < 8; ++t) {
        float4 a0 = *(const float4*)(xrow + t * 32);
        float4 a1 = *(const float4*)(xrow + t * 32 + 4);
        bf16x8 f;
        f[0] = (short)f2bf(a0.x); f[1] = (short)f2bf(a0.y);
        f[2] = (short)f2bf(a0.z); f[3] = (short)f2bf(a0.w);
        f[4] = (short)f2bf(a1.x); f[5] = (short)f2bf(a1.y);
        f[6] = (short)f2bf(a1.z); f[7] = (short)f2bf(a1.w);
        afrag[t] = f;
    }

#pragma unroll
    for (int s = 0; s < 6; ++s) {
        f32x4 acc = {0.f, 0.f, 0.f, 0.f};
#pragma unroll
        for (int t = 0; t < 8; ++t) {
            bf16x8 bfrag = *((const bf16x8*)sB + (s * 8 + t) * 64 + L);
            acc = __builtin_amdgcn_mfma_f32_16x16x32_bf16(afrag[t], bfrag, acc, 0, 0, 0);
        }
        int col = (s & 1) * 16 + lane16;
#pragma unroll
        for (int r = 0; r < 4; ++r) {
            int row = mt * 16 + quad * 4 + r;
            if (s < 2) Q[(size_t)row * HS + col] = acc[r];
            else if (s < 4) Kb[(size_t)row * HS + col] = f2bf(acc[r]);
            else Vb[(size_t)row * HS + col] = f2bf(acc[r]);
        }
    }
}

// ---------------- Fused per-node edge pass (unchanged from R8) ----------------
// 32-lane group per node; 4 edge slots x 8 lanes; bf16 K/V (64B/edge gathers).
// Writes EVERY node (zeros for empty segments) -> out needs no init pass.
__global__ __launch_bounds__(256) void fused_agg_kernel(
        const int* __restrict__ rowstart, const int* __restrict__ sorted_dst,
        const float* __restrict__ Q, const unsigned short* __restrict__ Kb,
        const unsigned short* __restrict__ Vb, float* __restrict__ out, int N) {
    int lane = threadIdx.x & 31;
    int n = blockIdx.x * 8 + (threadIdx.x >> 5);
    if (n >= N) return;
    int slot = lane >> 3;  // edge slot 0..3
    int sub = lane & 7;    // lane within slot
    int beg = rowstart[n], end = rowstart[n + 1];
    float4 qf = *(const float4*)(Q + (size_t)n * HS + sub * 4);
    float4 acc = make_float4(0.f, 0.f, 0.f, 0.f);
    float den = 0.f;

    for (int base = beg; base < end; base += 32) {
        int dreg = (base + lane < end) ? sorted_dst[base + lane] : 0;
        int cnt = min(32, end - base);
        for (int j = 0; j < cnt; j += 4) {
            int eidx = j + slot;
            int d = __shfl(dreg, eidx, 32);
            bool valid = (base + eidx) < end;
            u16x4 k4 = *(const u16x4*)(Kb + (size_t)d * HS + sub * 4);
            float p = qf.x * bf2f(k4[0]) + qf.y * bf2f(k4[1]) +
                      qf.z * bf2f(k4[2]) + qf.w * bf2f(k4[3]);
            p += __shfl_xor(p, 1, 32);
            p += __shfl_xor(p, 2, 32);
            p += __shfl_xor(p, 4, 32);
            float ex = valid ? __expf(p * 0.17677669529663687f) : 0.f;  // 1/sqrt(32)
            den += ex;
            u16x4 v4 = *(const u16x4*)(Vb + (size_t)d * HS + sub * 4);
            acc.x += ex * bf2f(v4[0]);
            acc.y += ex * bf2f(v4[1]);
            acc.z += ex * bf2f(v4[2]);
            acc.w += ex * bf2f(v4[3]);
        }
    }
    // sum the 4 edge slots (xor over slot bits 3,4)
#pragma unroll
    for (int off = 8; off <= 16; off <<= 1) {
        acc.x += __shfl_xor(acc.x, off, 32);
        acc.y += __shfl_xor(acc.y, off, 32);
        acc.z += __shfl_xor(acc.z, off, 32);
        acc.w += __shfl_xor(acc.w, off, 32);
        den += __shfl_xor(den, off, 32);
    }
    if (lane < 8) {
        float4 o = make_float4(0.f, 0.f, 0.f, 0.f);
        if (end > beg) {
            float rd = 1.f / den;
            o = make_float4(acc.x * rd, acc.y * rd, acc.z * rd, acc.w * rd);
        }
        *(float4*)(out + (size_t)n * HS + lane * 4) = o;
    }
}

extern "C" void kernel_launch(void* const* d_in, const int* in_sizes, int n_in,
                              void* d_out, int out_size, void* d_ws, size_t ws_size,
                              hipStream_t stream) {
    const float* X  = (const float*)d_in[0];
    const int*   ei = (const int*)d_in[1];
    const float* Wq = (const float*)d_in[2];
    const float* Wk = (const float*)d_in[3];
    const float* Wv = (const float*)d_in[4];

    int N = in_sizes[0] / N_INPUT;
    int E = in_sizes[1] / 2;
    const int* src = ei;
    const int* dst = ei + E;
    int cap = E / 8 + 4096;  // per-group bin capacity (binomial sigma ~433)

    // ws layout: Q[N*32] fp32; Kb,Vb[N*32] bf16; deg[N], rowstart[N+4],
    // cursor[N], bsum[256], boff[256], gcount[8(+pad)], sorted_dst[E],
    // bins[8*cap] unsigned.  ~52 MB.
    float* ws = (float*)d_ws;
    float* Q = ws;
    unsigned short* Kb = (unsigned short*)(Q + (size_t)N * HS);
    unsigned short* Vb = Kb + (size_t)N * HS;
    int* deg = (int*)(Vb + (size_t)N * HS);
    int* rowstart = deg + N;
    int* cursor = rowstart + N + 4;
    int* bsum = cursor + N;
    int* boff = bsum + 256;
    int* gcount = boff + 256;
    int* sorted_dst = gcount + 16;
    unsigned* bins = (unsigned*)(sorted_dst + E);
    float* out = (float*)d_out;

    int sblocks = (N + SE - 1) / SE;  // 98
    init_kernel<<<128, 256, 0, stream>>>(deg, gcount, N);
    bin_kernel<<<2048, 256, 0, stream>>>(src, dst, deg, bins, gcount, E, N, cap);
    block_reduce_kernel<<<sblocks, SB, 0, stream>>>(deg, bsum, N);
    scan_sums_kernel<<<1, SB, 0, stream>>>(bsum, boff, sblocks, rowstart, N, E);
    emit_kernel<<<sblocks, SB, 0, stream>>>(deg, boff, rowstart, cursor, N);
    scatter2_kernel<<<2048, 256, 0, stream>>>(bins, gcount, cursor, sorted_dst, cap, N);

    int mtiles = (N + 15) / 16;
    qkv_mfma_kernel<<<(mtiles + 3) / 4, 256, 0, stream>>>(X, Wq, Wk, Wv, Q, Kb, Vb, N);

    fused_agg_kernel<<<(N + 7) / 8, 256, 0, stream>>>(rowstart, sorted_dst, Q, Kb, Vb, out, N);
}

// Round 10
// 370.477 us; speedup vs baseline: 6.9656x; 6.9656x over previous
//
#include <hip/hip_runtime.h>

#define N_INPUT 256
#define HS 32
#define SB 256   // scan block threads
#define SE 1024  // elems per scan block
#define LBUF 4096

typedef __attribute__((ext_vector_type(8))) short bf16x8;
typedef __attribute__((ext_vector_type(4))) float f32x4;
typedef __attribute__((ext_vector_type(4))) unsigned short u16x4;

// fp32 -> bf16 bits, round-to-nearest-even
__device__ __forceinline__ unsigned short f2bf(float f) {
    unsigned u = __float_as_uint(f);
    unsigned r = u + 0x7FFFu + ((u >> 16) & 1u);
    return (unsigned short)(r >> 16);
}
__device__ __forceinline__ float bf2f(unsigned short u) {
    return __uint_as_float((unsigned)u << 16);
}

// ---------------- CSR build ----------------
// R9 postmortem: wave-aggregated atomicAdd onto 8 gcount addresses = 196K
// same-address RMWs serialized at ~12ns -> 2.3 ms. Fix: LDS-aggregate per
// block (block-local atomics), ONE global gcount atomic per block at the end
// (2048 total over 8 line-padded counters), coalesced buffer copy-out.

__global__ void init_kernel(int* __restrict__ deg, int* __restrict__ gcount, int N) {
    int i = blockIdx.x * blockDim.x + threadIdx.x;
    int stride = gridDim.x * blockDim.x;
    for (int j = i; j < N; j += stride) deg[j] = 0;
    if (i < 256) gcount[i] = 0;
}

// group g = blockIdx&7 (XCD round-robin) strides the edge list; in-range
// edges -> LDS buffer (expected fill 781 +- 26, LBUF=4096 >100 sigma; clamp
// guard). Pack: (src-nlo)<<17 | dst (N/8<2^14, dst<2^17). deg counted inline.
__global__ __launch_bounds__(256) void bin_kernel(
        const int* __restrict__ src, const int* __restrict__ dst,
        int* __restrict__ deg, unsigned* __restrict__ bins,
        int* __restrict__ gcount, int E, int N, int cap) {
    __shared__ unsigned lbuf[LBUF];
    __shared__ int lcount;
    __shared__ int gbase;
    int g = blockIdx.x & 7;
    int nlo = (int)(((long long)N * g) >> 3);
    int nhi = (int)(((long long)N * (g + 1)) >> 3);
    if (threadIdx.x == 0) lcount = 0;
    __syncthreads();
    int lane = threadIdx.x & 63;
    int stride = (gridDim.x >> 3) * blockDim.x;
    for (int e = (blockIdx.x >> 3) * blockDim.x + threadIdx.x; e < E; e += stride) {
        int s = src[e];
        int d = dst[e];
        bool inr = (s >= nlo) && (s < nhi);
        unsigned long long mask = __ballot(inr);
        if (inr) {
            int prefix = __popcll(mask & ((1ull << lane) - 1ull));
            int leader = __ffsll((unsigned long long)mask) - 1;
            int pos = 0;
            if (lane == leader) pos = atomicAdd(&lcount, __popcll(mask));
            pos = __shfl(pos, leader, 64);
            int idx = pos + prefix;
            if (idx < LBUF) lbuf[idx] = ((unsigned)(s - nlo) << 17) | (unsigned)d;
            atomicAdd(deg + s, 1);
        }
    }
    __syncthreads();
    int cnt = min(lcount, LBUF);
    if (threadIdx.x == 0) gbase = atomicAdd(gcount + g * 32, cnt);
    __syncthreads();
    unsigned* mybin = bins + (size_t)g * cap + gbase;
    for (int i = threadIdx.x; i < cnt; i += 256) mybin[i] = lbuf[i];
}

// 3-kernel device-wide exclusive scan (R6; R5's single-block scan was 231 us).
__global__ __launch_bounds__(SB) void block_reduce_kernel(
        const int* __restrict__ deg, int* __restrict__ bsum, int N) {
    __shared__ int s[SB];
    int blk = blockIdx.x, t = threadIdx.x;
    int base = blk * SE;
    int sum = 0;
#pragma unroll
    for (int i = 0; i < SE / SB; ++i) {
        int idx = base + i * SB + t;  // coalesced
        if (idx < N) sum += deg[idx];
    }
    s[t] = sum;
    __syncthreads();
    for (int off = SB / 2; off > 0; off >>= 1) {
        if (t < off) s[t] += s[t + off];
        __syncthreads();
    }
    if (t == 0) bsum[blk] = s[0];
}

__global__ __launch_bounds__(SB) void scan_sums_kernel(
        const int* __restrict__ bsum, int* __restrict__ boff, int nblocks,
        int* __restrict__ rowstart, int N, int E) {
    __shared__ int s[SB];
    int t = threadIdx.x;
    int v = (t < nblocks) ? bsum[t] : 0;
    s[t] = v;
    __syncthreads();
    for (int off = 1; off < SB; off <<= 1) {
        int u = (t >= off) ? s[t - off] : 0;
        __syncthreads();
        s[t] += u;
        __syncthreads();
    }
    if (t < nblocks) boff[t] = s[t] - v;  // exclusive block offset
    if (t == 0) rowstart[N] = E;
}

__global__ __launch_bounds__(SB) void emit_kernel(
        const int* __restrict__ deg, const int* __restrict__ boff,
        int* __restrict__ rowstart, int* __restrict__ cursor, int N) {
    __shared__ int s[SB];
    int blk = blockIdx.x, t = threadIdx.x;
    int base = blk * SE + t * 4;
    int4 d = make_int4(0, 0, 0, 0);
    if (base + 3 < N) {
        d = *(const int4*)(deg + base);
    } else {
        if (base + 0 < N) d.x = deg[base + 0];
        if (base + 1 < N) d.y = deg[base + 1];
        if (base + 2 < N) d.z = deg[base + 2];
    }
    int tsum = d.x + d.y + d.z + d.w;
    s[t] = tsum;
    __syncthreads();
    for (int off = 1; off < SB; off <<= 1) {
        int u = (t >= off) ? s[t - off] : 0;
        __syncthreads();
        s[t] += u;
        __syncthreads();
    }
    int pre = boff[blk] + s[t] - tsum;  // exclusive prefix of this thread's 1st elem
    int4 r;
    r.x = pre;
    r.y = r.x + d.x;
    r.z = r.y + d.y;
    r.w = r.z + d.z;
    if (base + 3 < N) {
        *(int4*)(rowstart + base) = r;
        *(int4*)(cursor + base) = r;
    } else {
        if (base + 0 < N) { rowstart[base + 0] = r.x; cursor[base + 0] = r.x; }
        if (base + 1 < N) { rowstart[base + 1] = r.y; cursor[base + 1] = r.y; }
        if (base + 2 < N) { rowstart[base + 2] = r.z; cursor[base + 2] = r.z; }
    }
}

// group g scatters only its own bin: reads 800KB sequential, writes its
// 800KB sorted_dst region, cursor atomics XCD-local -- everything L2-resident.
__global__ __launch_bounds__(256) void scatter2_kernel(
        const unsigned* __restrict__ bins, const int* __restrict__ gcount,
        int* __restrict__ cursor, int* __restrict__ sorted_dst, int cap, int N) {
    int g = blockIdx.x & 7;
    int nlo = (int)(((long long)N * g) >> 3);
    const unsigned* mybin = bins + (size_t)g * cap;
    int cnt = gcount[g * 32];
    int stride = (gridDim.x >> 3) * blockDim.x;
    for (int i = (blockIdx.x >> 3) * blockDim.x + threadIdx.x; i < cnt; i += stride) {
        unsigned p = mybin[i];
        int s = nlo + (int)(p >> 17);
        int d = (int)(p & 0x1FFFFu);
        int pos = atomicAdd(cursor + s, 1);
        sorted_dst[pos] = d;
    }
}

// ---------------- Fused Q/K/V projection (MFMA, unchanged from R8) ----------------
__global__ __launch_bounds__(256) void qkv_mfma_kernel(
        const float* __restrict__ X, const float* __restrict__ Wq,
        const float* __restrict__ Wk, const float* __restrict__ Wv,
        float* __restrict__ Q, unsigned short* __restrict__ Kb,
        unsigned short* __restrict__ Vb, int N) {
    __shared__ unsigned short sBw[6 * 8 * 64 * 8];  // 48 KB, frag-ordered bf16 W

    int tid = threadIdx.x;
    for (int i = 0; i < 12; ++i) {
        int c = tid + i * 256;
        int s = c >> 9;
        int t = (c >> 6) & 7;
        int L = c & 63;
        const float* wm = (s < 2) ? Wq : (s < 4) ? Wk : Wv;
        const float* wsrc = wm + (size_t)(t * 32 + (L >> 4) * 8) * HS + (s & 1) * 16 + (L & 15);
        unsigned e0 = f2bf(wsrc[0 * HS]) | ((unsigned)f2bf(wsrc[1 * HS]) << 16);
        unsigned e1 = f2bf(wsrc[2 * HS]) | ((unsigned)f2bf(wsrc[3 * HS]) << 16);
        unsigned e2 = f2bf(wsrc[4 * HS]) | ((unsigned)f2bf(wsrc[5 * HS]) << 16);
        unsigned e3 = f2bf(wsrc[6 * HS]) | ((unsigned)f2bf(wsrc[7 * HS]) << 16);
        ((uint4*)sBw)[c] = make_uint4(e0, e1, e2, e3);
    }
    __syncthreads();

    int wave = tid >> 6;
    int L = tid & 63;
    int quad = L >> 4;
    int lane16 = L & 15;
    int mt = blockIdx.x * 4 + wave;
    if (mt * 16 >= N) return;  // no barriers past this point

    const float* xrow = X + (size_t)(mt * 16 + lane16) * N_INPUT + quad * 8;
    bf16x8 afrag[8];
#pragma unroll
    for (int t = 0; t < 8; ++t) {
        float4 a0 = *(const float4*)(xrow + t * 32);
        float4 a1 = *(const float4*)(xrow + t * 32 + 4);
        bf16x8 f;
        f[0] = (short)f2bf(a0.x); f[1] = (short)f2bf(a0.y);
        f[2] = (short)f2bf(a0.z); f[3] = (short)f2bf(a0.w);
        f[4] = (short)f2bf(a1.x); f[5] = (short)f2bf(a1.y);
        f[6] = (short)f2bf(a1.z); f[7] = (short)f2bf(a1.w);
        afrag[t] = f;
    }

#pragma unroll
    for (int s = 0; s < 6; ++s) {
        f32x4 acc = {0.f, 0.f, 0.f, 0.f};
#pragma unroll
        for (int t = 0; t < 8; ++t) {
            bf16x8 bfrag = *((const bf16x8*)sBw + (s * 8 + t) * 64 + L);
            acc = __builtin_amdgcn_mfma_f32_16x16x32_bf16(afrag[t], bfrag, acc, 0, 0, 0);
        }
        int col = (s & 1) * 16 + lane16;
#pragma unroll
        for (int r = 0; r < 4; ++r) {
            int row = mt * 16 + quad * 4 + r;
            if (s < 2) Q[(size_t)row * HS + col] = acc[r];
            else if (s < 4) Kb[(size_t)row * HS + col] = f2bf(acc[r]);
            else Vb[(size_t)row * HS + col] = f2bf(acc[r]);
        }
    }
}

// ---------------- Fused per-node edge pass (unchanged from R8) ----------------
// 32-lane group per node; 4 edge slots x 8 lanes; bf16 K/V (64B/edge gathers).
// Writes EVERY node (zeros for empty segments) -> out needs no init pass.
__global__ __launch_bounds__(256) void fused_agg_kernel(
        const int* __restrict__ rowstart, const int* __restrict__ sorted_dst,
        const float* __restrict__ Q, const unsigned short* __restrict__ Kb,
        const unsigned short* __restrict__ Vb, float* __restrict__ out, int N) {
    int lane = threadIdx.x & 31;
    int n = blockIdx.x * 8 + (threadIdx.x >> 5);
    if (n >= N) return;
    int slot = lane >> 3;  // edge slot 0..3
    int sub = lane & 7;    // lane within slot
    int beg = rowstart[n], end = rowstart[n + 1];
    float4 qf = *(const float4*)(Q + (size_t)n * HS + sub * 4);
    float4 acc = make_float4(0.f, 0.f, 0.f, 0.f);
    float den = 0.f;

    for (int base = beg; base < end; base += 32) {
        int dreg = (base + lane < end) ? sorted_dst[base + lane] : 0;
        int cnt = min(32, end - base);
        for (int j = 0; j < cnt; j += 4) {
            int eidx = j + slot;
            int d = __shfl(dreg, eidx, 32);
            bool valid = (base + eidx) < end;
            u16x4 k4 = *(const u16x4*)(Kb + (size_t)d * HS + sub * 4);
            float p = qf.x * bf2f(k4[0]) + qf.y * bf2f(k4[1]) +
                      qf.z * bf2f(k4[2]) + qf.w * bf2f(k4[3]);
            p += __shfl_xor(p, 1, 32);
            p += __shfl_xor(p, 2, 32);
            p += __shfl_xor(p, 4, 32);
            float ex = valid ? __expf(p * 0.17677669529663687f) : 0.f;  // 1/sqrt(32)
            den += ex;
            u16x4 v4 = *(const u16x4*)(Vb + (size_t)d * HS + sub * 4);
            acc.x += ex * bf2f(v4[0]);
            acc.y += ex * bf2f(v4[1]);
            acc.z += ex * bf2f(v4[2]);
            acc.w += ex * bf2f(v4[3]);
        }
    }
    // sum the 4 edge slots (xor over slot bits 3,4)
#pragma unroll
    for (int off = 8; off <= 16; off <<= 1) {
        acc.x += __shfl_xor(acc.x, off, 32);
        acc.y += __shfl_xor(acc.y, off, 32);
        acc.z += __shfl_xor(acc.z, off, 32);
        acc.w += __shfl_xor(acc.w, off, 32);
        den += __shfl_xor(den, off, 32);
    }
    if (lane < 8) {
        float4 o = make_float4(0.f, 0.f, 0.f, 0.f);
        if (end > beg) {
            float rd = 1.f / den;
            o = make_float4(acc.x * rd, acc.y * rd, acc.z * rd, acc.w * rd);
        }
        *(float4*)(out + (size_t)n * HS + lane * 4) = o;
    }
}

extern "C" void kernel_launch(void* const* d_in, const int* in_sizes, int n_in,
                              void* d_out, int out_size, void* d_ws, size_t ws_size,
                              hipStream_t stream) {
    const float* X  = (const float*)d_in[0];
    const int*   ei = (const int*)d_in[1];
    const float* Wq = (const float*)d_in[2];
    const float* Wk = (const float*)d_in[3];
    const float* Wv = (const float*)d_in[4];

    int N = in_sizes[0] / N_INPUT;
    int E = in_sizes[1] / 2;
    const int* src = ei;
    const int* dst = ei + E;
    int cap = E / 8 + 4096;  // per-group bin capacity

    // ws layout: Q[N*32] fp32; Kb,Vb[N*32] bf16; deg[N], rowstart[N+4],
    // cursor[N], bsum[256], boff[256], gcount[256 line-padded], sorted_dst[E],
    // bins[8*cap] unsigned.
    float* ws = (float*)d_ws;
    float* Q = ws;
    unsigned short* Kb = (unsigned short*)(Q + (size_t)N * HS);
    unsigned short* Vb = Kb + (size_t)N * HS;
    int* deg = (int*)(Vb + (size_t)N * HS);
    int* rowstart = deg + N;
    int* cursor = rowstart + N + 4;
    int* bsum = cursor + N;
    int* boff = bsum + 256;
    int* gcount = boff + 256;
    int* sorted_dst = gcount + 256;
    unsigned* bins = (unsigned*)(sorted_dst + E);
    float* out = (float*)d_out;

    int sblocks = (N + SE - 1) / SE;  // 98
    init_kernel<<<128, 256, 0, stream>>>(deg, gcount, N);
    bin_kernel<<<2048, 256, 0, stream>>>(src, dst, deg, bins, gcount, E, N, cap);
    block_reduce_kernel<<<sblocks, SB, 0, stream>>>(deg, bsum, N);
    scan_sums_kernel<<<1, SB, 0, stream>>>(bsum, boff, sblocks, rowstart, N, E);
    emit_kernel<<<sblocks, SB, 0, stream>>>(deg, boff, rowstart, cursor, N);
    scatter2_kernel<<<2048, 256, 0, stream>>>(bins, gcount, cursor, sorted_dst, cap, N);

    int mtiles = (N + 15) / 16;
    qkv_mfma_kernel<<<(mtiles + 3) / 4, 256, 0, stream>>>(X, Wq, Wk, Wv, Q, Kb, Vb, N);

    fused_agg_kernel<<<(N + 7) / 8, 256, 0, stream>>>(rowstart, sorted_dst, Q, Kb, Vb, out, N);
}